// Round 1
// baseline (510.676 us; speedup 1.0000x reference)
//
#include <hip/hip_runtime.h>
#include <hip/hip_bf16.h>
#include <cstdint>

#define TPB 256

constexpr int B = 8, C = 684, H = 64, W = 256;
constexpr int HID = 256, A = 512, K = 11;
constexpr int HW = H * W;      // 16384
constexpr int KK = K * K;      // 121
constexpr int FW_LD = 128;     // padded tap stride

__device__ __forceinline__ float fast_tanh(float x) {
    // tanh(x) = 1 - 2/(e^{2x}+1); saturates correctly at +/-inf
    float e = __expf(2.f * x);
    return 1.f - 2.f * __builtin_amdgcn_rcpf(e + 1.f);
}

// query[b,a] = hidden[b,:] @ W_h[:,a] + b_h[a]
__global__ void query_kernel(const float* __restrict__ hidden,
                             const float* __restrict__ W_h,
                             const float* __restrict__ b_h,
                             float* __restrict__ query) {
    int idx = blockIdx.x * TPB + threadIdx.x;   // B*A = 4096
    int b = idx >> 9, a = idx & (A - 1);
    float q = b_h[a];
    const float* hb = hidden + b * HID;
    for (int k = 0; k < HID; ++k)
        q = fmaf(hb[k], W_h[k * A + a], q);
    query[idx] = q;
}

// fwT[a][t] = sum_c conv_w[c,0,t] * W_att[c,a]   (t in [0,121), padded to 128 with 0)
__global__ void fw_kernel(const float* __restrict__ conv_w,
                          const float* __restrict__ W_att,
                          float* __restrict__ fwT) {
    int idx = blockIdx.x * TPB + threadIdx.x;   // A*FW_LD = 65536
    int t = idx >> 9, a = idx & (A - 1);        // t uniform per block
    float v = 0.f;
    if (t < KK) {
        for (int ch = 0; ch < 512; ++ch)
            v = fmaf(conv_w[ch * KK + t], W_att[ch * A + a], v);
    }
    fwT[a * FW_LD + t] = v;
}

// energy[b,h,w] = sum_a tanh(query[b,a] + cov[b,h,w,a] + trans[b,a,h,w]) * W_alpha[a] + b_alpha
// cov[b,h,w,a] = sum_t nb(b, h+r-5, w+c-5) * fwT[a][t]
__global__ __launch_bounds__(TPB, 2) void energy_kernel(
    const float* __restrict__ alpha_sum,
    const float* __restrict__ trans,
    const float* __restrict__ query,
    const float* __restrict__ fwT,
    const float* __restrict__ W_alpha,
    const float* __restrict__ b_alpha,
    float* __restrict__ energy) {
    const int h = blockIdx.x;
    const int b = blockIdx.y;
    const int w = threadIdx.x;

    __shared__ float nb[K][272];
    const float* as_b = alpha_sum + b * HW;
    for (int idx = threadIdx.x; idx < K * 266; idx += TPB) {
        int r = idx / 266, j = idx % 266;
        int gh = h + r - 5, gw = j - 5;
        float v = 0.f;
        if (gh >= 0 && gh < H && gw >= 0 && gw < W)
            v = as_b[gh * W + gw];
        nb[r][j] = v;
    }
    __syncthreads();

    // per-pixel 11x11 neighborhood cached in VGPRs (static-indexed)
    float nbr[KK];
#pragma unroll
    for (int r = 0; r < K; ++r)
#pragma unroll
        for (int c = 0; c < K; ++c)
            nbr[r * K + c] = nb[r][w + c];

    const float* qb = query + b * A;
    const float* tb = trans + (size_t)b * A * HW + h * W + w;
    float eacc = 0.f;
    for (int a = 0; a < A; ++a) {
        const float* f = fwT + a * FW_LD;   // uniform -> s_load
        float cov = 0.f;
#pragma unroll
        for (int t = 0; t < KK; ++t)
            cov = fmaf(nbr[t], f[t], cov);
        float x = qb[a] + cov + tb[(size_t)a * HW];
        eacc = fmaf(fast_tanh(x), W_alpha[a], eacc);
    }
    energy[(b * H + h) * W + w] = eacc + b_alpha[0];
}

// per-batch online max + sum(exp(e-m)*mask); writes maxv[b], 1/(sum+1e-10)
__global__ void softmax_reduce_kernel(const float* __restrict__ energy,
                                      const float* __restrict__ mask,
                                      float* __restrict__ maxv,
                                      float* __restrict__ invd) {
    const int b = blockIdx.x;
    const float* e = energy + b * HW;
    const float* mk = mask + b * HW;
    float m = -1e30f, s = 0.f;
    for (int i = threadIdx.x; i < HW; i += TPB) {
        float v = e[i];
        float nm = fmaxf(m, v);
        s = s * __expf(m - nm) + __expf(v - nm) * mk[i];
        m = nm;
    }
    __shared__ float sm[TPB], ss[TPB];
    sm[threadIdx.x] = m; ss[threadIdx.x] = s;
    __syncthreads();
    for (int str = TPB / 2; str > 0; str >>= 1) {
        if (threadIdx.x < str) {
            float m2 = sm[threadIdx.x + str], s2 = ss[threadIdx.x + str];
            float m1 = sm[threadIdx.x], s1 = ss[threadIdx.x];
            float nm = fmaxf(m1, m2);
            sm[threadIdx.x] = nm;
            ss[threadIdx.x] = s1 * __expf(m1 - nm) + s2 * __expf(m2 - nm);
        }
        __syncthreads();
    }
    if (threadIdx.x == 0) {
        maxv[b] = sm[0];
        invd[b] = 1.f / (ss[0] + 1e-10f);
    }
}

// alpha, new_alpha_sum, masked alpha
__global__ void alpha_kernel(const float* __restrict__ energy,
                             const float* __restrict__ mask,
                             const float* __restrict__ alpha_sum,
                             const float* __restrict__ maxv,
                             const float* __restrict__ invd,
                             float* __restrict__ out_alpha,
                             float* __restrict__ out_nas,
                             float* __restrict__ am) {
    int i = blockIdx.x * TPB + threadIdx.x;   // B*HW
    int b = i >> 14;
    float al = __expf(energy[i] - maxv[b]) * mask[i] * invd[b];
    out_alpha[i] = al;
    out_nas[i] = al + alpha_sum[i];
    am[i] = (al > 0.02f) ? al : 0.f;
}

// context[b,c] = sum_hw am[b,hw] * feat[b,c,hw]
__global__ void context_kernel(const float* __restrict__ feat,
                               const float* __restrict__ am,
                               float* __restrict__ out_ctx) {
    const int c = blockIdx.x, b = blockIdx.y;
    const float4* f4 = (const float4*)(feat + ((size_t)b * C + c) * HW);
    const float4* a4 = (const float4*)(am + b * HW);
    float s = 0.f;
    for (int i = threadIdx.x; i < HW / 4; i += TPB) {
        float4 fv = f4[i];
        float4 av = a4[i];
        s += fv.x * av.x + fv.y * av.y + fv.z * av.z + fv.w * av.w;
    }
    for (int off = 32; off > 0; off >>= 1) s += __shfl_down(s, off, 64);
    __shared__ float ls[TPB / 64];
    int lane = threadIdx.x & 63, wid = threadIdx.x >> 6;
    if (lane == 0) ls[wid] = s;
    __syncthreads();
    if (threadIdx.x == 0) {
        float t = 0.f;
        for (int i = 0; i < TPB / 64; ++i) t += ls[i];
        out_ctx[b * C + c] = t;
    }
}

extern "C" void kernel_launch(void* const* d_in, const int* in_sizes, int n_in,
                              void* d_out, int out_size, void* d_ws, size_t ws_size,
                              hipStream_t stream) {
    const float* cnn_features = (const float*)d_in[0];
    const float* trans        = (const float*)d_in[1];
    const float* hidden       = (const float*)d_in[2];
    const float* alpha_sum    = (const float*)d_in[3];
    const float* image_mask   = (const float*)d_in[4];
    const float* W_h          = (const float*)d_in[5];
    const float* b_h          = (const float*)d_in[6];
    const float* conv_w       = (const float*)d_in[7];
    const float* W_att        = (const float*)d_in[8];
    const float* W_alpha      = (const float*)d_in[9];
    const float* b_alpha      = (const float*)d_in[10];

    float* out       = (float*)d_out;
    float* out_ctx   = out;               // B*C
    float* out_alpha = out + B * C;       // B*HW
    float* out_nas   = out_alpha + B * HW;

    float* ws     = (float*)d_ws;
    float* query  = ws;                   // 4096
    float* fwT    = query + B * A;        // 65536
    float* energy = fwT + A * FW_LD;      // 131072
    float* maxv   = energy + B * HW;      // 8
    float* invd   = maxv + 8;             // 8
    float* am     = invd + 8;             // 131072

    hipLaunchKernelGGL(query_kernel, dim3((B * A) / TPB), dim3(TPB), 0, stream,
                       hidden, W_h, b_h, query);
    hipLaunchKernelGGL(fw_kernel, dim3((A * FW_LD) / TPB), dim3(TPB), 0, stream,
                       conv_w, W_att, fwT);
    hipLaunchKernelGGL(energy_kernel, dim3(H, B), dim3(TPB), 0, stream,
                       alpha_sum, trans, query, fwT, W_alpha, b_alpha, energy);
    hipLaunchKernelGGL(softmax_reduce_kernel, dim3(B), dim3(TPB), 0, stream,
                       energy, image_mask, maxv, invd);
    hipLaunchKernelGGL(alpha_kernel, dim3(B * HW / TPB), dim3(TPB), 0, stream,
                       energy, image_mask, alpha_sum, maxv, invd,
                       out_alpha, out_nas, am);
    hipLaunchKernelGGL(context_kernel, dim3(C, B), dim3(TPB), 0, stream,
                       cnn_features, am, out_ctx);
}